// Round 2
// baseline (88.081 us; speedup 1.0000x reference)
//
#include <hip/hip_runtime.h>
#include <math.h>

#define N_    1024
#define RANK_ 8
#define M_    8192

typedef float vf2 __attribute__((ext_vector_type(2)));

// Static device scratch, fully rewritten every call.
__device__ __align__(16) float2 g_Y   [RANK_ * M_];      // DFT stage-1 intermediate
__device__ __align__(16) float2 g_HreP[(RANK_/2) * M_];  // {Re Hf[2p][m], Re Hf[2p+1][m]}
__device__ __align__(16) float2 g_HimP[(RANK_/2) * M_];  // {Im Hf[2p][m], Im Hf[2p+1][m]}
__device__ __align__(16) float  g_sw  [N_ * RANK_];      // softmax(W, axis=1)
__device__ __align__(16) float2 g_step[N_ * RANK_];      // {cos,sin}(2pi * tau/32): per-thread m-stride rotor step

// v_sin_f32 / v_cos_f32: input in REVOLUTIONS (cdna4_isa.md §3); reduce via fract.
__device__ __forceinline__ float cos2pi(float rev) { return __builtin_amdgcn_cosf(rev); }
__device__ __forceinline__ float sin2pi(float rev) { return __builtin_amdgcn_sinf(rev); }
__device__ __forceinline__ float fractf_(float x)  { return __builtin_amdgcn_fractf(x); }

// ============ kernel A: fused softplus -> stage-1 DFT (blocks 0..255) + softmax(W)/step-table (blocks 256..259) ============
// stage 1: Y[r][t1][k2] = sum_t2 softplus(H)[r][t1+64*t2] * W128^(k2*t2),  8192 = 64(t1) x 128(t2)
__global__ __launch_bounds__(256) void k_pre(const float* __restrict__ H,
                                             const float* __restrict__ W,
                                             const float* __restrict__ tau) {
    if (blockIdx.x < 256) {
        __shared__ float spl[256];          // spl[h*128+j] = softplus(H[r, 2(b&31)+h + 64*j])
        __shared__ float cs[128], sn[128];  // twiddle table, 128 distinct angles
        int t    = threadIdx.x;
        int b    = blockIdx.x;
        int r    = b >> 5;
        int half = t >> 7;                  // wave-uniform (waves 0,1 -> 0; waves 2,3 -> 1)
        int j    = t & 127;
        int t1   = ((b & 31) << 1) | half;
        float x = H[r * M_ + t1 + (j << 6)];
        spl[half * 128 + j] = (x > 20.f) ? x : log1pf(expf(x));
        if (t < 128) {
            float rev = (float)t * (1.0f / 128.0f);
            cs[t] = cos2pi(rev);
            sn[t] = sin2pi(rev);
        }
        __syncthreads();
        int k2 = j;
        float ar = 0.f, ai = 0.f;
        for (int t2 = 0; t2 < 128; ++t2) {
            float xv = spl[half * 128 + t2];          // wave-uniform -> LDS broadcast
            int id = (k2 * t2) & 127;
            ar = fmaf(xv,  cs[id], ar);               // x * (c - i s)
            ai = fmaf(xv, -sn[id], ai);
        }
        g_Y[b * 256 + t] = make_float2(ar, ai);       // == g_Y[r*8192 + t1*128 + k2]
    } else {
        int n = (blockIdx.x - 256) * 256 + threadIdx.x;
        if (n < N_) {
            float v[RANK_];
            float mx = -1e30f;
#pragma unroll
            for (int r = 0; r < RANK_; ++r) { v[r] = W[n * RANK_ + r]; mx = fmaxf(mx, v[r]); }
            float s = 0.f;
#pragma unroll
            for (int r = 0; r < RANK_; ++r) { v[r] = expf(v[r] - mx); s += v[r]; }
            float inv = 1.f / s;
#pragma unroll
            for (int r = 0; r < RANK_; ++r) g_sw[n * RANK_ + r] = v[r] * inv;
            // rotor step factor for k_main: e^{-2pi*i * tau*256/M} stored as {cos, sin} of tau/32 rev
#pragma unroll
            for (int r = 0; r < RANK_; ++r) {
                float d = tau[n * RANK_ + r] * (1.0f / 32.0f);  // 256/8192 rev per m-step
                float fr = fractf_(d);
                g_step[n * RANK_ + r] = make_float2(cos2pi(fr), sin2pi(fr));
            }
        }
    }
}

// ============ kernel B: stage-2 DFT with rotation recurrence; rectangular pair-layout epilogue ============
// Hf[r][k] = sum_t1 Y[r][t1][k&127] * e^{-2pi*i*t1*k/8192}
__global__ void k_dft2() {
    int tid = blockIdx.x * blockDim.x + threadIdx.x;   // 65536 threads
    int k = tid & 8191;
    int r = tid >> 13;
    int j = k & 127;
    const float2* y = g_Y + r * M_ + j;
    float rev = (float)k * (1.0f / 8192.0f);           // exact in fp32
    float cr = cos2pi(rev), sr = sin2pi(rev);
    float c = 1.f, s = 0.f;                            // rotor at t1 = 0
    float ar = 0.f, ai = 0.f;
    for (int t1 = 0; t1 < 64; ++t1) {
        float2 yv = y[t1 * 128];                       // coalesced (lanes j-consecutive)
        // (yr + i*yi) * (c - i*s)
        ar = fmaf(yv.x, c, ar); ar = fmaf(yv.y, s, ar);
        ai = fmaf(yv.y, c, ai); ai = fmaf(-yv.x, s, ai);
        // angle += rev :  cos(a+b) = c*cr - s*sr ; sin(a+b) = s*cr + c*sr
        float cn = fmaf(c, cr, -(s * sr));
        float sn_ = fmaf(s, cr,  (c * sr));
        c = cn; s = sn_;
    }
    // pair-of-r layout: g_HreP[p][k].{x,y} = Re Hf[2p|2p+1][k]
    int p = r >> 1, h = r & 1;
    reinterpret_cast<float*>(g_HreP)[((p * M_ + k) << 1) | h] = ar;
    reinterpret_cast<float*>(g_HimP)[((p * M_ + k) << 1) | h] = ai;
}

// ============ kernel C: out[n,m] = sum_r Re( sw*e^{-2pi*i*tau*m/M} * Hf[r,m] ) via rotor recurrence ============
// Thread t of block (bx,by): m = bx*2048 + t + 256*s (s=0..7), n = by*4 + i (i=0..3).
// Per (n,r): rotor P = sw*e^{-2pi*i*tau*m/M} held rectangular, advanced by the precomputed
// per-(n,r) step factor each m-step (4 pk-fma) — ZERO transcendentals in the steady loop.
#define S_  8   // m-steps per thread
#define NT  4   // n-rows per thread
__global__ __launch_bounds__(256) void k_main(const float* __restrict__ tau,
                                              float* __restrict__ out,
                                              int out_size_floats) {
    int t   = threadIdx.x;
    int m_t = blockIdx.x * (256 * S_) + t;            // first m this thread owns
    int n0  = blockIdx.y * NT;
    float fm = (float)m_t * (1.0f / 8192.0f);         // m_t/M, exact

    // Rotor state packed over r-pairs: Pr2[i][p] = {Pr(2p), Pr(2p+1)} for row n0+i
    vf2 Pr2[NT][4], Pi2[NT][4], dc2[NT][4], ds2[NT][4];
#pragma unroll
    for (int i = 0; i < NT; ++i) {
        int nb = (n0 + i) * RANK_;
        const float4* tp = reinterpret_cast<const float4*>(&tau[nb]);
        float4 t0 = tp[0], t1 = tp[1];
        const float4* wp = reinterpret_cast<const float4*>(&g_sw[nb]);
        float4 w0 = wp[0], w1 = wp[1];
        float tv[RANK_] = {t0.x, t0.y, t0.z, t0.w, t1.x, t1.y, t1.z, t1.w};
        float wv[RANK_] = {w0.x, w0.y, w0.z, w0.w, w1.x, w1.y, w1.z, w1.w};
#pragma unroll
        for (int p = 0; p < 4; ++p) {
            float2 st0 = g_step[nb + 2 * p];
            float2 st1 = g_step[nb + 2 * p + 1];
            dc2[i][p] = (vf2){st0.x, st1.x};
            ds2[i][p] = (vf2){st0.y, st1.y};
            float th0 = fractf_(tv[2 * p]     * fm);
            float th1 = fractf_(tv[2 * p + 1] * fm);
            Pr2[i][p] = (vf2){ wv[2 * p] * cos2pi(th0),  wv[2 * p + 1] * cos2pi(th1)};
            Pi2[i][p] = (vf2){-wv[2 * p] * sin2pi(th0), -wv[2 * p + 1] * sin2pi(th1)};
        }
    }

#pragma unroll
    for (int s = 0; s < S_; ++s) {
        int m = m_t + (s << 8);
        vf2 hre[4], him[4];
#pragma unroll
        for (int p = 0; p < 4; ++p) {
            float2 a = g_HreP[p * M_ + m];
            float2 b = g_HimP[p * M_ + m];
            hre[p] = (vf2){a.x, a.y};
            him[p] = (vf2){b.x, b.y};
        }
#pragma unroll
        for (int i = 0; i < NT; ++i) {
            vf2 aA = (vf2){0.f, 0.f}, aB = (vf2){0.f, 0.f};
#pragma unroll
            for (int p = 0; p < 4; ++p) {
                aA = __builtin_elementwise_fma(Pr2[i][p], hre[p], aA);  // += Pr*Hre
                aB = __builtin_elementwise_fma(Pi2[i][p], him[p], aB);  // += Pi*Him
            }
            float res = (aA.x + aA.y) - (aB.x + aB.y);                  // Re(P*Hf) summed over r
            int idx = (n0 + i) * M_ + m;
            if (idx < out_size_floats) out[idx] = res;
        }
        if (s < S_ - 1) {
            // advance rotors: P *= (dc - i*ds):  Pr' = Pr*dc + Pi*ds ; Pi' = Pi*dc - Pr*ds
#pragma unroll
            for (int i = 0; i < NT; ++i)
#pragma unroll
                for (int p = 0; p < 4; ++p) {
                    vf2 npr = __builtin_elementwise_fma(Pr2[i][p], dc2[i][p], Pi2[i][p] * ds2[i][p]);
                    vf2 npi = __builtin_elementwise_fma(Pi2[i][p], dc2[i][p], -(Pr2[i][p] * ds2[i][p]));
                    Pr2[i][p] = npr; Pi2[i][p] = npi;
                }
        }
    }
}

extern "C" void kernel_launch(void* const* d_in, const int* in_sizes, int n_in,
                              void* d_out, int out_size, void* d_ws, size_t ws_size,
                              hipStream_t stream) {
    const float* W   = (const float*)d_in[0];   // (N, RANK)
    const float* H   = (const float*)d_in[1];   // (RANK, M)
    const float* tau = (const float*)d_in[2];   // (N, RANK)

    float* out = (float*)d_out;

    k_pre  <<<dim3(256 + N_ / 256),            dim3(256), 0, stream>>>(H, W, tau);
    k_dft2 <<<dim3((RANK_ * M_) / 256),        dim3(256), 0, stream>>>();
    k_main <<<dim3(M_ / (256 * S_), N_ / NT),  dim3(256), 0, stream>>>(tau, out, out_size);
}